// Round 5
// baseline (250.623 us; speedup 1.0000x reference)
//
#include <hip/hip_runtime.h>

// Round 5: q_w=32 restructure. 512-thr blocks = 2 q-subtiles(32q) x 4 k-groups(16 keys),
// 32x32x16 MFMA for PV, global_load_lds double-buffered staging (pre-swizzled source),
// one barrier/iter, 4-way split-K merge epilogue. Grid 256 (XCD-pinned batches).
//   d_in: 0=x [4,4096,256] f32, 1=mask [4,4096] i32, 2=Wk, 3=Wq, 4=Wv [256,256] f32
// ws: q f16 [B*T][C] (pre-scaled 1/16), k f16 [B*T][C], vt f16 [B][C][T]

typedef __attribute__((ext_vector_type(8)))  _Float16 f16x8;
typedef __attribute__((ext_vector_type(4)))  _Float16 f16x4;
typedef __attribute__((ext_vector_type(4)))  float    f32x4;
typedef __attribute__((ext_vector_type(16))) float    f32x16;

constexpr int Bb = 4;
constexpr int Tt = 4096;
constexpr int Cc = 256;
constexpr int BT = Bb * Tt;
constexpr int NI = 64;                 // iterations: 4 groups x 16 keys x 64 = 4096

#define MFMA16(a, b, c) __builtin_amdgcn_mfma_f32_16x16x32_f16((a), (b), (c), 0, 0, 0)
#define MFMA32(a, b, c) __builtin_amdgcn_mfma_f32_32x32x16_f16((a), (b), (c), 0, 0, 0)

__device__ __forceinline__ void gl16(const _Float16* gp, _Float16* lp) {
    __builtin_amdgcn_global_load_lds(
        (const __attribute__((address_space(1))) void*)gp,
        (__attribute__((address_space(3))) void*)lp, 16, 0, 0);
}

// ---------------- Kernel A: fused QKV projection (y = x @ W^T) ----------------
__global__ __launch_bounds__(256) void qkv_proj(
    const float* __restrict__ x,
    const float* __restrict__ Wq, const float* __restrict__ Wk,
    const float* __restrict__ Wv,
    _Float16* __restrict__ qo, _Float16* __restrict__ ko,
    _Float16* __restrict__ vto)
{
    extern __shared__ _Float16 sm[];
    _Float16* xs = sm;              // [128][264]
    _Float16* wsm = sm + 128 * 264; // [128][264]

    const int tid = threadIdx.x;
    const int m0  = blockIdx.x * 128;
    const int ny  = blockIdx.y;
    const int mat = ny >> 1;              // 0=q 1=k 2=v
    const int d0  = (ny & 1) * 128;
    const float* W = (mat == 0) ? Wq : (mat == 1 ? Wk : Wv);

#pragma unroll
    for (int i = 0; i < 32; ++i) {
        int flat = i * 256 + tid;
        int r = flat >> 6, c4 = (flat & 63) << 2;
        float4 v = *reinterpret_cast<const float4*>(x + (size_t)(m0 + r) * Cc + c4);
        f16x4 h = { (_Float16)v.x, (_Float16)v.y, (_Float16)v.z, (_Float16)v.w };
        *reinterpret_cast<f16x4*>(xs + r * 264 + c4) = h;
    }
#pragma unroll
    for (int i = 0; i < 32; ++i) {
        int flat = i * 256 + tid;
        int r = flat >> 6, c4 = (flat & 63) << 2;
        float4 v = *reinterpret_cast<const float4*>(W + (size_t)(d0 + r) * Cc + c4);
        f16x4 h = { (_Float16)v.x, (_Float16)v.y, (_Float16)v.z, (_Float16)v.w };
        *reinterpret_cast<f16x4*>(wsm + r * 264 + c4) = h;
    }
    __syncthreads();

    const int w = tid >> 6, lane = tid & 63;
    const int lr = lane & 15, lg = lane >> 4;

    f32x4 acc[2][8] = {};

#pragma unroll
    for (int kc = 0; kc < 8; ++kc) {
        const int c0 = kc * 32 + lg * 8;
        f16x8 xf[2], wf[8];
#pragma unroll
        for (int mb = 0; mb < 2; ++mb)
            xf[mb] = *reinterpret_cast<const f16x8*>(xs + (w * 32 + mb * 16 + lr) * 264 + c0);
#pragma unroll
        for (int db = 0; db < 8; ++db)
            wf[db] = *reinterpret_cast<const f16x8*>(wsm + (db * 16 + lr) * 264 + c0);
        if (mat != 2) {
#pragma unroll
            for (int mb = 0; mb < 2; ++mb)
#pragma unroll
                for (int db = 0; db < 8; ++db)
                    acc[mb][db] = MFMA16(wf[db], xf[mb], acc[mb][db]);
        } else {
#pragma unroll
            for (int mb = 0; mb < 2; ++mb)
#pragma unroll
                for (int db = 0; db < 8; ++db)
                    acc[mb][db] = MFMA16(xf[mb], wf[db], acc[mb][db]);
        }
    }

    if (mat != 2) {
        const float sc = (mat == 0) ? 0.0625f : 1.0f;
        _Float16* dst = (mat == 0) ? qo : ko;
#pragma unroll
        for (int mb = 0; mb < 2; ++mb)
#pragma unroll
            for (int db = 0; db < 8; ++db) {
                int m = m0 + w * 32 + mb * 16 + lr;
                int d = d0 + db * 16 + lg * 4;
                f32x4 a = acc[mb][db];
                f16x4 h = { (_Float16)(a.x * sc), (_Float16)(a.y * sc),
                            (_Float16)(a.z * sc), (_Float16)(a.w * sc) };
                *reinterpret_cast<f16x4*>(dst + (size_t)m * Cc + d) = h;
            }
    } else {
#pragma unroll
        for (int mb = 0; mb < 2; ++mb)
#pragma unroll
            for (int db = 0; db < 8; ++db) {
                int d = d0 + db * 16 + lr;
                int m = m0 + w * 32 + mb * 16 + lg * 4;
                int bb = m >> 12, t = m & (Tt - 1);
                f32x4 a = acc[mb][db];
                f16x4 h = { (_Float16)a.x, (_Float16)a.y, (_Float16)a.z, (_Float16)a.w };
                *reinterpret_cast<f16x4*>(vto + (size_t)bb * Cc * Tt + (size_t)d * Tt + t) = h;
            }
    }
}

// ---------------- Kernel B: flash attention ----------------
// LDS map (bytes): [0,131072) 2 x [4 groups][K 8KB | V 8KB] double buffer
//                  [131072,143360) per-wave P buffers [8][32][24] f16
//                  [143360,144384) mex f32[2][4][32]; [144384,145408) lex
// epilogue reuses [0,135168) as oex f32[4][32][264]
__global__ __launch_bounds__(512, 2) void attn_kernel(
    const _Float16* __restrict__ qb, const _Float16* __restrict__ kb,
    const _Float16* __restrict__ vtb, const int* __restrict__ mask,
    float* __restrict__ outp)
{
    extern __shared__ char smraw[];
    _Float16* sm  = (_Float16*)smraw;
    float*    oexf = (float*)smraw;
    float*    mex  = (float*)(smraw + 143360);
    float*    lex  = (float*)(smraw + 144384);

    const int tid = threadIdx.x, w = tid >> 6, lane = tid & 63;
    const int g = w & 3, qs = w >> 2;
    const int l15 = lane & 15, l4 = lane >> 4;   // 16x16 decomp
    const int l31 = lane & 31, l5 = lane >> 5;   // 32x32 decomp

    const int bid = blockIdx.x;
    const int b   = (bid & 7) >> 1;                       // batch -> XCD pair
    const int qt  = ((bid >> 3) << 1) | (bid & 1);        // [0,64)
    const int q0  = qt * 64;
    const size_t base = (size_t)b * Tt * Cc;
    const int* maskb = mask + (size_t)b * Tt;
    const _Float16* kg = kb + base;
    const _Float16* vg = vtb + base;                      // [C][T] for batch b

    // Q fragments: B-operand of 16x16x32: Q[q = qh*16+l15][c = kc*32 + l4*8 + j]
    f16x8 qf[2][8];
#pragma unroll
    for (int qh = 0; qh < 2; ++qh)
#pragma unroll
        for (int kc = 0; kc < 8; ++kc)
            qf[qh][kc] = *reinterpret_cast<const f16x8*>(
                qb + base + (size_t)(q0 + qs * 32 + qh * 16 + l15) * Cc + kc * 32 + l4 * 8);

    // staging source offsets (elements, k0-independent)
    int koff_st[8], voff_st[8];
#pragma unroll
    for (int j = 0; j < 8; ++j) {
        int row = 2 * j + l5;                      // key row in tile
        koff_st[j] = row * 256 + ((l31 ^ (row & 7)) * 8);
        int rowc = j * 32 + (lane >> 1);           // C row in tile
        voff_st[j] = rowc * Tt + (lane & 1) * 8;
    }
    // QK A-frag read offsets (elements, swizzle-matched)
    int koff_rd[8];
#pragma unroll
    for (int kc = 0; kc < 8; ++kc)
        koff_rd[kc] = l15 * 256 + (((kc * 4 + l4) ^ (lane & 7)) * 8);

    _Float16* pw = (_Float16*)(smraw + 131072) + w * 768;   // [32][24]

    auto STAGE = [&](int it, int bufsel) {
        const int k0 = (it * 4 + g) * 16;
        if (qs == 0) {
            _Float16* dst = sm + bufsel * 32768 + g * 8192;
#pragma unroll
            for (int j = 0; j < 8; ++j)
                gl16(kg + (size_t)k0 * 256 + koff_st[j], dst + j * 512);
        } else {
            _Float16* dst = sm + bufsel * 32768 + g * 8192 + 4096;
#pragma unroll
            for (int j = 0; j < 8; ++j)
                gl16(vg + (size_t)k0 + voff_st[j], dst + j * 512);
        }
    };

    f32x16 o[8] = {};                       // O^T[d = dt*32 + dmap(reg,l5)][q = l31]
    float m0r = -60.f, m1r = -60.f, l0r = 0.f, l1r = 0.f;

    STAGE(0, 0);
    int4 mcur = *reinterpret_cast<const int4*>(maskb + g * 16 + l4 * 4);
    asm volatile("s_waitcnt vmcnt(0)" ::: "memory");
    __syncthreads();

    int cur = 0;
#pragma unroll 1
    for (int it = 0; it < NI; ++it) {
        int4 mnext = mcur;
        if (it + 1 < NI) {
            STAGE(it + 1, cur ^ 1);
            mnext = *reinterpret_cast<const int4*>(
                maskb + ((it + 1) * 4 + g) * 16 + l4 * 4);
        }

        _Float16* kb_ = sm + cur * 32768 + g * 8192;
        _Float16* vb_ = kb_ + 4096;

        // S = K Q^T : D[key = l4*4 + r][q = qh*16 + l15]
        f32x4 s40 = { 0.f, 0.f, 0.f, 0.f }, s41 = { 0.f, 0.f, 0.f, 0.f };
#pragma unroll
        for (int kc = 0; kc < 8; ++kc) {
            f16x8 kf = *reinterpret_cast<const f16x8*>(kb_ + koff_rd[kc]);
            s40 = MFMA16(kf, qf[0][kc], s40);
            s41 = MFMA16(kf, qf[1][kc], s41);
        }

        if (mcur.x == 0) { s40[0] = -1e30f; s41[0] = -1e30f; }
        if (mcur.y == 0) { s40[1] = -1e30f; s41[1] = -1e30f; }
        if (mcur.z == 0) { s40[2] = -1e30f; s41[2] = -1e30f; }
        if (mcur.w == 0) { s40[3] = -1e30f; s41[3] = -1e30f; }

        // online softmax (per qh; q = l15; keys spread over l4 groups)
        float t0 = fmaxf(fmaxf(s40[0], s40[1]), fmaxf(s40[2], s40[3]));
        float t1 = fmaxf(fmaxf(s41[0], s41[1]), fmaxf(s41[2], s41[3]));
        t0 = fmaxf(t0, __shfl_xor(t0, 16, 64)); t0 = fmaxf(t0, __shfl_xor(t0, 32, 64));
        t1 = fmaxf(t1, __shfl_xor(t1, 16, 64)); t1 = fmaxf(t1, __shfl_xor(t1, 32, 64));

        if (__any(t0 > m0r + 8.f || t1 > m1r + 8.f)) {     // defer-max
            float mn0 = fmaxf(m0r, t0), mn1 = fmaxf(m1r, t1);
            float c0 = __expf(m0r - mn0), c1 = __expf(m1r - mn1);
            m0r = mn0; m1r = mn1; l0r *= c0; l1r *= c1;
            float cs = (lane & 16) ? c1 : c0;
#pragma unroll
            for (int dt = 0; dt < 8; ++dt) o[dt] *= cs;
        }

        float rs0 = 0.f, rs1 = 0.f;
#pragma unroll
        for (int r = 0; r < 4; ++r) {
            float p0 = __expf(s40[r] - m0r); s40[r] = p0; rs0 += p0;
            float p1 = __expf(s41[r] - m1r); s41[r] = p1; rs1 += p1;
        }
        rs0 += __shfl_xor(rs0, 16, 64); rs0 += __shfl_xor(rs0, 32, 64);
        rs1 += __shfl_xor(rs1, 16, 64); rs1 += __shfl_xor(rs1, 32, 64);
        l0r += rs0; l1r += rs1;

        // P -> pw[q][k] (f16), reread as 32x32 B-frag
        {
            f16x4 h0 = { (_Float16)s40[0], (_Float16)s40[1], (_Float16)s40[2], (_Float16)s40[3] };
            f16x4 h1 = { (_Float16)s41[0], (_Float16)s41[1], (_Float16)s41[2], (_Float16)s41[3] };
            *reinterpret_cast<f16x4*>(pw + (l15) * 24 + l4 * 4)      = h0;
            *reinterpret_cast<f16x4*>(pw + (16 + l15) * 24 + l4 * 4) = h1;
        }
        f16x8 pf = *reinterpret_cast<const f16x8*>(pw + l31 * 24 + l5 * 8);

        // O^T += V^T P^T  (32x32x16)
#pragma unroll
        for (int dt = 0; dt < 8; ++dt) {
            f16x8 vf = *reinterpret_cast<const f16x8*>(vb_ + dt * 512 + l31 * 16 + l5 * 8);
            o[dt] = MFMA32(vf, pf, o[dt]);
        }

        mcur = mnext;
        asm volatile("s_waitcnt vmcnt(0)" ::: "memory");
        __syncthreads();
        cur ^= 1;
    }

    // ---- epilogue: 4-group merge, two q-subtile passes ----
    if (lane < 32) {
        mex[qs * 128 + g * 32 + l31] = (lane & 16) ? m1r : m0r;
        lex[qs * 128 + g * 32 + l31] = (lane & 16) ? l1r : l0r;
    }
    __syncthreads();

#pragma unroll 1
    for (int s = 0; s < 2; ++s) {
        if (qs == s) {
            float mm = (lane & 16) ? m1r : m0r;
            float ms = fmaxf(fmaxf(mex[s * 128 + l31],      mex[s * 128 + 32 + l31]),
                             fmaxf(mex[s * 128 + 64 + l31], mex[s * 128 + 96 + l31]));
            float sc = __expf(mm - ms);
            float* og = oexf + g * 8448;
#pragma unroll
            for (int dt = 0; dt < 8; ++dt)
#pragma unroll
                for (int j = 0; j < 4; ++j) {
                    f32x4 vv = { o[dt][4 * j + 0] * sc, o[dt][4 * j + 1] * sc,
                                 o[dt][4 * j + 2] * sc, o[dt][4 * j + 3] * sc };
                    *reinterpret_cast<f32x4*>(og + l31 * 264 + dt * 32 + j * 8 + 4 * l5) = vv;
                }
        }
        __syncthreads();
        {
            int q = tid >> 4, d0 = (tid & 15) * 16;
            float mA = mex[s * 128 + q],      mB = mex[s * 128 + 32 + q];
            float mC = mex[s * 128 + 64 + q], mD = mex[s * 128 + 96 + q];
            float ms = fmaxf(fmaxf(mA, mB), fmaxf(mC, mD));
            float lt = lex[s * 128 + q] * __expf(mA - ms)
                     + lex[s * 128 + 32 + q] * __expf(mB - ms)
                     + lex[s * 128 + 64 + q] * __expf(mC - ms)
                     + lex[s * 128 + 96 + q] * __expf(mD - ms);
            float inv = 1.f / lt;
#pragma unroll
            for (int i = 0; i < 4; ++i) {
                f32x4 a = *reinterpret_cast<const f32x4*>(oexf + q * 264 + d0 + 4 * i);
#pragma unroll
                for (int g2 = 1; g2 < 4; ++g2) {
                    f32x4 t = *reinterpret_cast<const f32x4*>(
                        oexf + g2 * 8448 + q * 264 + d0 + 4 * i);
                    a[0] += t[0]; a[1] += t[1]; a[2] += t[2]; a[3] += t[3];
                }
                a[0] *= inv; a[1] *= inv; a[2] *= inv; a[3] *= inv;
                *reinterpret_cast<f32x4*>(
                    outp + base + (size_t)(q0 + s * 32 + q) * Cc + d0 + 4 * i) = a;
            }
        }
        __syncthreads();
    }
}

extern "C" void kernel_launch(void* const* d_in, const int* in_sizes, int n_in,
                              void* d_out, int out_size, void* d_ws, size_t ws_size,
                              hipStream_t stream)
{
    (void)in_sizes; (void)n_in; (void)out_size; (void)ws_size;
    const float* x   = (const float*)d_in[0];
    const int*  mask = (const int*)d_in[1];
    const float* Wk  = (const float*)d_in[2];
    const float* Wq  = (const float*)d_in[3];
    const float* Wv  = (const float*)d_in[4];
    float* out = (float*)d_out;

    _Float16* q  = (_Float16*)d_ws;
    _Float16* k  = q + (size_t)BT * Cc;
    _Float16* vt = k + (size_t)BT * Cc;

    dim3 gA(128, 6), blkA(256);
    size_t ldsA = (size_t)(128 + 128) * 264 * sizeof(_Float16);
    qkv_proj<<<gA, blkA, ldsA, stream>>>(x, Wq, Wk, Wv, q, k, vt);

    dim3 gB(256), blkB(512);
    size_t ldsB = 145408;
    attn_kernel<<<gB, blkB, ldsB, stream>>>(q, k, vt, mask, out);
}